// Round 1
// baseline (511.936 us; speedup 1.0000x reference)
//
#include <hip/hip_runtime.h>
#include <math.h>

#define B_ROWS   1024
#define IN_FEAT  76800
#define OUT_FEAT 10
#define NF4      (IN_FEAT / 4)        // 19200 float4 per row
#define W_ELEMS  (OUT_FEAT * IN_FEAT) // 768000
#define EPSQ     1e-5f

// ---------------- K1: per-block partial sums of |W| ----------------
__global__ __launch_bounds__(256) void k_wabs_partial(const float* __restrict__ W,
                                                      float* __restrict__ partials) {
    const int tid = threadIdx.x, bid = blockIdx.x;
    float s = 0.f;
    for (int i = bid * 256 + tid; i < W_ELEMS; i += 256 * 256) s += fabsf(W[i]);
    #pragma unroll
    for (int off = 32; off >= 1; off >>= 1) s += __shfl_down(s, off, 64);
    __shared__ float red[4];
    const int wv = tid >> 6, ln = tid & 63;
    if (ln == 0) red[wv] = s;
    __syncthreads();
    if (tid == 0) partials[bid] = red[0] + red[1] + red[2] + red[3];
}

// ---------------- K2: final reduce -> scale_w = 1/clip(mean|W|, eps) ----------------
__global__ __launch_bounds__(256) void k_wscale(const float* __restrict__ partials,
                                                float* __restrict__ scale_w) {
    const int tid = threadIdx.x;
    float s = partials[tid];
    #pragma unroll
    for (int off = 32; off >= 1; off >>= 1) s += __shfl_down(s, off, 64);
    __shared__ float red[4];
    const int wv = tid >> 6, ln = tid & 63;
    if (ln == 0) red[wv] = s;
    __syncthreads();
    if (tid == 0) {
        float mean = (red[0] + red[1] + red[2] + red[3]) / (float)W_ELEMS;
        scale_w[0] = 1.0f / fmaxf(mean, EPSQ);
    }
}

// ---------------- K3: ternary-quantize weights into BYTE planes ----------------
// wq8[o*IN_FEAT + k] = code+1 in {0,1,2}. Byte planes let the GEMV decode one
// weight with a single v_cvt_f32_ubyteN (vs shift+and+cvt on the 2-bit pack).
__global__ __launch_bounds__(256) void k_wpack8(const float* __restrict__ W,
                                                const float* __restrict__ scale_w,
                                                unsigned char* __restrict__ wq8) {
    const int k = blockIdx.x * 256 + threadIdx.x;
    if (k >= IN_FEAT) return;
    const float s = scale_w[0];
    #pragma unroll
    for (int o = 0; o < OUT_FEAT; ++o) {
        float c = fminf(1.f, fmaxf(-1.f, rintf(W[o * IN_FEAT + k] * s)));
        wq8[o * IN_FEAT + k] = (unsigned char)((int)c + 1);
    }
}

// ---------------- K4: per-row absmax -> sx[row] = 127/clip(max|x|, eps) ----------------
// Pure streaming pass, no barriers in the hot loop: should run at the HBM roofline.
// Side effect: leaves most of x resident in the 256 MB Infinity Cache for K5.
__global__ __launch_bounds__(256) void k_rowmax(const float* __restrict__ x,
                                                float* __restrict__ sxrow) {
    const int tid = threadIdx.x, row = blockIdx.x;
    const float4* __restrict__ xr = (const float4*)(x + (size_t)row * IN_FEAT);
    float m = 0.f;
    #pragma unroll 5
    for (int j = 0; j < 75; ++j) {          // 75*256 = 19200 = NF4 exactly
        float4 v = xr[tid + j * 256];
        m = fmaxf(m, fmaxf(fmaxf(fabsf(v.x), fabsf(v.y)), fmaxf(fabsf(v.z), fabsf(v.w))));
    }
    #pragma unroll
    for (int off = 32; off >= 1; off >>= 1) m = fmaxf(m, __shfl_down(m, off, 64));
    __shared__ float red[4];
    const int wv = tid >> 6, ln = tid & 63;
    if (ln == 0) red[wv] = m;
    __syncthreads();
    if (tid == 0) {
        float mm = fmaxf(fmaxf(red[0], red[1]), fmaxf(red[2], red[3]));
        sxrow[row] = 127.0f / fmaxf(mm, EPSQ);
    }
}

// ---------------- K5: quantize + GEMV + bias + softmax, one block per row ----------------
// x re-read is mostly L3-resident from K4. Byte-plane decode: per element per output
// it's one v_cvt_f32_ubyteN + one fma. sum(q*(c+1)) - sum(q) recovers sum(q*c).
__global__ __launch_bounds__(256) void k_gemv(const float* __restrict__ x,
                                              const unsigned char* __restrict__ wq8,
                                              const float* __restrict__ bias,
                                              const float* __restrict__ scale_w,
                                              const float* __restrict__ sxrow,
                                              float* __restrict__ out) {
    __shared__ float racc[4][12];
    __shared__ float fin[12];
    __shared__ float lgs[OUT_FEAT];

    const int tid = threadIdx.x, row = blockIdx.x;
    const float sx = sxrow[row];
    const float sw = scale_w[0];
    const float4* __restrict__ xr = (const float4*)(x + (size_t)row * IN_FEAT);

    float acc[OUT_FEAT] = {0.f, 0.f, 0.f, 0.f, 0.f, 0.f, 0.f, 0.f, 0.f, 0.f};
    float sq = 0.f;

    #pragma unroll 2
    for (int j = 0; j < 75; ++j) {          // 75*256 = 19200 = NF4 exactly
        const int idx = tid + j * 256;
        float4 v = xr[idx];
        float q0 = rintf(v.x * sx);         // |x*sx| <= 127 -> no clamp needed
        float q1 = rintf(v.y * sx);
        float q2 = rintf(v.z * sx);
        float q3 = rintf(v.w * sx);
        sq += (q0 + q1) + (q2 + q3);
        #pragma unroll
        for (int o = 0; o < OUT_FEAT; ++o) {
            unsigned int w = ((const unsigned int*)(wq8 + (size_t)o * IN_FEAT))[idx];
            acc[o] = fmaf(q0, (float)(w & 0xffu),
                     fmaf(q1, (float)((w >> 8) & 0xffu),
                     fmaf(q2, (float)((w >> 16) & 0xffu),
                     fmaf(q3, (float)(w >> 24), acc[o]))));
        }
    }

    // ---- block reduce 11 values (10 accs + sum_q) across 4 waves ----
    float vals[11];
    #pragma unroll
    for (int t = 0; t < OUT_FEAT; ++t) vals[t] = acc[t];
    vals[10] = sq;
    #pragma unroll
    for (int t = 0; t < 11; ++t) {
        #pragma unroll
        for (int off = 32; off >= 1; off >>= 1) vals[t] += __shfl_down(vals[t], off, 64);
    }
    const int wv = tid >> 6, ln = tid & 63;
    if (ln == 0) {
        #pragma unroll
        for (int t = 0; t < 11; ++t) racc[wv][t] = vals[t];
    }
    __syncthreads();
    if (tid < 11) fin[tid] = racc[0][tid] + racc[1][tid] + racc[2][tid] + racc[3][tid];
    __syncthreads();
    if (tid < OUT_FEAT) {
        float inv = 1.0f / (sx * sw);       // dequant: sum q*c / (sx*sw)
        lgs[tid] = (fin[tid] - fin[10]) * inv + bias[tid];
    }
    __syncthreads();
    if (tid < OUT_FEAT) {
        float m = lgs[0];
        #pragma unroll
        for (int o = 1; o < OUT_FEAT; ++o) m = fmaxf(m, lgs[o]);
        float den = 0.f;
        #pragma unroll
        for (int o = 0; o < OUT_FEAT; ++o) den += __expf(lgs[o] - m);
        float e = __expf(lgs[tid] - m);
        out[row * OUT_FEAT + tid] = e / den;
    }
}

extern "C" void kernel_launch(void* const* d_in, const int* in_sizes, int n_in,
                              void* d_out, int out_size, void* d_ws, size_t ws_size,
                              hipStream_t stream) {
    const float* x    = (const float*)d_in[0];
    const float* Wmat = (const float*)d_in[1];
    const float* bias = (const float*)d_in[2];
    float* out = (float*)d_out;

    char* wsb = (char*)d_ws;
    float* scale_w      = (float*)wsb;                   // 1 float
    float* partials     = (float*)(wsb + 256);           // 256 floats
    float* sxrow        = (float*)(wsb + 4096);          // 1024 floats
    unsigned char* wq8  = (unsigned char*)(wsb + 8192);  // 768000 bytes (10 planes)
    // total workspace: ~776 KB

    k_wabs_partial<<<256, 256, 0, stream>>>(Wmat, partials);
    k_wscale<<<1, 256, 0, stream>>>(partials, scale_w);
    k_wpack8<<<(IN_FEAT + 255) / 256, 256, 0, stream>>>(Wmat, scale_w, wq8);
    k_rowmax<<<B_ROWS, 256, 0, stream>>>(x, sxrow);      // right before gemv: max L3 freshness
    k_gemv<<<B_ROWS, 256, 0, stream>>>(x, wq8, bias, scale_w, sxrow, out);
}